// Round 9
// baseline (777.142 us; speedup 1.0000x reference)
//
#include <hip/hip_runtime.h>

// ---- problem constants ----
#define SEQ     2048
#define HIDDEN  4544          // 71 * 64
#define NHEAD   71
#define HD      64
#define QKV_OUT 4672          // (71+2)*64

typedef __bf16    bf16;
typedef _Float16  f16;
typedef __bf16    bf16x8 __attribute__((ext_vector_type(8)));
typedef __bf16    bf16x4 __attribute__((ext_vector_type(4)));
typedef _Float16  f16x4  __attribute__((ext_vector_type(4)));
typedef _Float16  f16x8  __attribute__((ext_vector_type(8)));
typedef float     f32x4  __attribute__((ext_vector_type(4)));

// async global->LDS, 16B per lane. ldsbase must be wave-uniform (HW adds lane*16B);
// the GLOBAL address is per-lane and must be lane-distinct.
__device__ inline void gl2lds16(const void* g, void* ldsbase) {
  __builtin_amdgcn_global_load_lds(
      (const __attribute__((address_space(1))) unsigned int*)g,
      (__attribute__((address_space(3))) unsigned int*)ldsbase,
      16, 0, 0);
}

// ---------------- fp32 -> bf16 convert (vectorized) ----------------
__global__ void cvt_f32_bf16_k(const float* __restrict__ in, bf16* __restrict__ out, int n4) {
  int i = blockIdx.x * blockDim.x + threadIdx.x;
  if (i >= n4) return;
  float4 f = ((const float4*)in)[i];
  bf16x4 o;
  o[0] = (bf16)f.x; o[1] = (bf16)f.y; o[2] = (bf16)f.z; o[3] = (bf16)f.w;
  *(bf16x4*)(out + (size_t)i * 4) = o;
}

// reg-stage 8 f32 -> 8 bf16 -> one ds_write_b128 (same RTNE cast as the cvt kernel)
__device__ inline void stage8f(const float* __restrict__ s, bf16* d) {
  float4 a = *(const float4*)s;
  float4 b = *(const float4*)(s + 4);
  bf16x8 o;
  o[0] = (bf16)a.x; o[1] = (bf16)a.y; o[2] = (bf16)a.z; o[3] = (bf16)a.w;
  o[4] = (bf16)b.x; o[5] = (bf16)b.y; o[6] = (bf16)b.z; o[7] = (bf16)b.w;
  *(bf16x8*)d = o;
}

// ---------------- bt-GEMM, BK=64: C[M x Nmat] = A[M x K] * Bf[Nmat x K]^T --------
// Round-4 proven 128x128 2-phase structure + T1 XCD swizzle. B is consumed directly
// from f32 (reg-staged + in-register bf16 convert) -- eliminates the two weight
// convert kernels (~251 MB of HBM traffic). A stays on the async gl2lds path.
// __syncthreads() drains both the A gl2lds (vmcnt) and the B ds_writes (lgkmcnt).
__global__ __launch_bounds__(256) void gemm_bt_k(const bf16* __restrict__ A,
                                                 const float* __restrict__ Bf,
                                                 float* __restrict__ C,
                                                 int K, int Nmat, int ldc) {
  __shared__ bf16 lA[2][128 * 32];   // [k-half][row*32 + k]
  __shared__ bf16 lB[2][128 * 32];
  const int t = threadIdx.x;
  const int lane = t & 63, w = t >> 6;

  // T1: bijective XCD swizzle (both call sites have nwg % 8 == 0)
  const int gx = gridDim.x;
  const int nwg = gx * gridDim.y;
  const int orig = blockIdx.y * gx + blockIdx.x;
  const int swz = (orig & 7) * (nwg >> 3) + (orig >> 3);
  const int m0 = (swz % gx) * 128;
  const int n0 = (swz / gx) * 128;

  const int wm = (w >> 1) * 64, wn = (w & 1) * 64;
  const int qi = lane & 15, grp = lane >> 4;

  const int r0 = t >> 2;            // 0..63: row within 64-row block
  const int c0 = (t & 3) * 8;       // 0,8,16,24: k offset within 32-slice
  const bf16* gA0 = A + (size_t)(m0 + r0) * K + c0;
  const bf16* gA1 = A + (size_t)(m0 + 64 + r0) * K + c0;
  int bR0 = n0 + r0;      if (bR0 >= Nmat) bR0 = Nmat - 1;
  int bR1 = n0 + 64 + r0; if (bR1 >= Nmat) bR1 = Nmat - 1;
  const float* gB0 = Bf + (size_t)bR0 * K + c0;
  const float* gB1 = Bf + (size_t)bR1 * K + c0;
  bf16* lA00 = &lA[0][0] + w * 512;          // (half0, rows 0-63)
  bf16* lA01 = &lA[0][2048] + w * 512;       // (half0, rows 64-127)
  bf16* lA10 = &lA[1][0] + w * 512;
  bf16* lA11 = &lA[1][2048] + w * 512;
  bf16* dB00 = &lB[0][t * 8];                // per-thread ds_write dests
  bf16* dB01 = &lB[0][2048 + t * 8];
  bf16* dB10 = &lB[1][t * 8];
  bf16* dB11 = &lB[1][2048 + t * 8];

  f32x4 acc[4][4] = {};
  for (int k0 = 0; k0 < K; k0 += 64) {
    __syncthreads();
    gl2lds16(gA0 + k0,      lA00);
    gl2lds16(gA1 + k0,      lA01);
    gl2lds16(gA0 + k0 + 32, lA10);
    gl2lds16(gA1 + k0 + 32, lA11);
    stage8f(gB0 + k0,      dB00);
    stage8f(gB1 + k0,      dB01);
    stage8f(gB0 + k0 + 32, dB10);
    stage8f(gB1 + k0 + 32, dB11);
    __syncthreads();
#pragma unroll
    for (int half = 0; half < 2; ++half) {
      bf16x8 af[4], bfv[4];
#pragma unroll
      for (int i = 0; i < 4; ++i)
        af[i] = *(const bf16x8*)&lA[half][(wm + i * 16 + qi) * 32 + grp * 8];
#pragma unroll
      for (int i = 0; i < 4; ++i)
        bfv[i] = *(const bf16x8*)&lB[half][(wn + i * 16 + qi) * 32 + grp * 8];
#pragma unroll
      for (int i = 0; i < 4; ++i)
#pragma unroll
        for (int j = 0; j < 4; ++j)
          acc[i][j] = __builtin_amdgcn_mfma_f32_16x16x32_bf16(af[i], bfv[j], acc[i][j], 0, 0, 0);
    }
  }

#pragma unroll
  for (int i = 0; i < 4; ++i) {
    const int row = m0 + wm + i * 16 + grp * 4;
#pragma unroll
    for (int j = 0; j < 4; ++j) {
      const int col = n0 + wn + j * 16 + qi;
      if (col < Nmat) {
#pragma unroll
        for (int r = 0; r < 4; ++r)
          C[(size_t)(row + r) * ldc + col] = acc[i][j][r];
      }
    }
  }
}

// ---------------- RoPE for Q + cos/sin tables (vectorized float4) ----------------
// Scale folds 1/8 AND log2(e) so attention can use exp2 directly.
#define QSCALE 0.18033688f   // 0.125 * 1.4426950408889634
__global__ __launch_bounds__(256) void rope_q_k(const float* __restrict__ fused,
                                                bf16* __restrict__ Qb,
                                                float* __restrict__ cs_tab,
                                                float* __restrict__ sn_tab) {
  const int s = blockIdx.x, t = threadIdx.x;
  __shared__ float cs[64], sn[64];
  if (t < 64) {
    int i = t & 31;
    double invf = pow(10000.0, -(double)i / 32.0);
    double ang = (double)s * invf;
    float c = (float)cos(ang), n = (float)sin(ang);
    cs[t] = c; sn[t] = n;
    cs_tab[s * 64 + t] = c;
    sn_tab[s * 64 + t] = n;
  }
  __syncthreads();
  const float* r0 = fused + (size_t)s * QKV_OUT;
  bf16* qrow = Qb + (size_t)s * HIDDEN;
  // 71 heads x 8 float4-chunks of the low half (d<32); pair with d+32.
  // cs[d] == cs[d^32], sn[d] == sn[d^32] by construction.
  for (int u = t; u < NHEAD * 8; u += 256) {
    const int head = u >> 3, c4 = (u & 7) * 4;    // d = c4..c4+3 (<32)
    const int e = head * 64 + c4;
    float4 lo = *(const float4*)(r0 + e);
    float4 hi = *(const float4*)(r0 + e + 32);
    float xl[4] = {lo.x, lo.y, lo.z, lo.w};
    float xh[4] = {hi.x, hi.y, hi.z, hi.w};
    bf16x4 qlo, qhi;
#pragma unroll
    for (int j = 0; j < 4; ++j) {
      const float c = cs[c4 + j], n = sn[c4 + j];
      qlo[j] = (bf16)((xl[j] * c - xh[j] * n) * QSCALE);
      qhi[j] = (bf16)((xh[j] * c + xl[j] * n) * QSCALE);
    }
    *(bf16x4*)(qrow + e) = qlo;
    *(bf16x4*)(qrow + e + 32) = qhi;
  }
}

// ---------------- K (roped) and V -> MFMA-operand-ordered global layouts ----------
// Vf pairs tt-subtiles so attention reads V as 16B/lane.
__global__ __launch_bounds__(64) void kvprep_k(const float* __restrict__ fused,
                                               const float* __restrict__ cs_tab,
                                               const float* __restrict__ sn_tab,
                                               bf16* __restrict__ Kf,
                                               f16* __restrict__ Vf) {
  const int t16 = blockIdx.x, lane = threadIdx.x;
  const int qi = lane & 15, grp = lane >> 4;
  const int s = t16 * 16 + qi;
  const float* krow = fused + (size_t)s * QKV_OUT + NHEAD * 64;
  const float* cs = cs_tab + s * 64;
  const float* sn = sn_tab + s * 64;
#pragma unroll
  for (int half = 0; half < 2; ++half) {
    bf16x8 o;
    const int d0 = half * 32 + grp * 8;
#pragma unroll
    for (int j = 0; j < 8; ++j) {
      int d = d0 + j;
      float x = krow[d], xp = krow[d ^ 32];
      float rot = (d < 32) ? -xp : xp;
      o[j] = (bf16)(x * cs[d] + rot * sn[d]);
    }
    *(bf16x8*)&Kf[(t16 * 2 + half) * 512 + lane * 8] = o;
  }
#pragma unroll
  for (int p = 0; p < 2; ++p) {
    f16x8 o;
#pragma unroll
    for (int h = 0; h < 2; ++h) {
      const int tt = p * 2 + h;
#pragma unroll
      for (int j = 0; j < 4; ++j)
        o[h * 4 + j] = (f16)fused[(size_t)(t16 * 16 + grp * 4 + j) * QKV_OUT + (NHEAD + 1) * 64 + tt * 16 + qi];
    }
    *(f16x8*)&Vf[t16 * 1024 + p * 512 + lane * 8] = o;
  }
}

// ---------------- causal MQA flash attention: 1 wave = (head, 32 q rows) ----------
// Round-4 proven structure (80 VGPR, no barriers in the kv loop, fl-LDS epilogue).
__global__ __launch_bounds__(64) void attn_k(const bf16* __restrict__ Qb,
                                             const bf16* __restrict__ Kf,
                                             const f16*  __restrict__ Vf,
                                             bf16* __restrict__ Ao) {
  __shared__ float fl[2 * 16 * 68];
  const int h = blockIdx.y;
  const int b32 = gridDim.x - 1 - blockIdx.x;   // big blocks first
  const int lane = threadIdx.x;
  const int qi = lane & 15, grp = lane >> 4;
  const int q0 = b32 * 32;
  const int lastT = b32 >> 1;

  bf16x8 qf[2][2];
#pragma unroll
  for (int qq = 0; qq < 2; ++qq) {
    const bf16* qb = Qb + (size_t)(q0 + qq * 16 + qi) * HIDDEN + h * 64 + grp * 8;
    qf[qq][0] = *(const bf16x8*)qb;
    qf[qq][1] = *(const bf16x8*)(qb + 32);
  }

  f32x4 o[2][4] = {};
  float l[2] = {0.f, 0.f};

  for (int kb = 0; kb <= lastT; ++kb) {
    const bf16* kfp = Kf + (size_t)kb * 4096 + lane * 8;
    bf16x8 kf[4][2];
#pragma unroll
    for (int kk = 0; kk < 4; ++kk) {
      kf[kk][0] = *(const bf16x8*)(kfp + kk * 1024);
      kf[kk][1] = *(const bf16x8*)(kfp + kk * 1024 + 512);
    }
    f32x4 s4[2][4];
#pragma unroll
    for (int qq = 0; qq < 2; ++qq)
#pragma unroll
      for (int kk = 0; kk < 4; ++kk) {
        f32x4 z = {};
        s4[qq][kk] = __builtin_amdgcn_mfma_f32_16x16x32_bf16(kf[kk][0], qf[qq][0], z, 0, 0, 0);
        s4[qq][kk] = __builtin_amdgcn_mfma_f32_16x16x32_bf16(kf[kk][1], qf[qq][1], s4[qq][kk], 0, 0, 0);
      }
    // V: 8 x 16B loads (paired-tt layout) — issued before softmax so latency hides
    const f16* vfp = Vf + (size_t)kb * 4096 + lane * 8;
    f16x4 vf[4][4];
#pragma unroll
    for (int kk = 0; kk < 4; ++kk)
#pragma unroll
      for (int p = 0; p < 2; ++p) {
        f16x8 v8 = *(const f16x8*)(vfp + kk * 1024 + p * 512);
#pragma unroll
        for (int j = 0; j < 4; ++j) {
          vf[kk][2 * p][j]     = v8[j];
          vf[kk][2 * p + 1][j] = v8[4 + j];
        }
      }

    if (kb == lastT) {
      const int dq = q0 - kb * 64 + qi;
#pragma unroll
      for (int qq = 0; qq < 2; ++qq)
#pragma unroll
        for (int kk = 0; kk < 4; ++kk)
#pragma unroll
          for (int r = 0; r < 4; ++r)
            if (kk * 16 + grp * 4 + r > dq + qq * 16) s4[qq][kk][r] = -1e30f;
    }
    // scores pre-scaled by log2(e): exp2 is the raw HW op
    f16x4 pf[2][4];
#pragma unroll
    for (int qq = 0; qq < 2; ++qq) {
      float ls = 0.f;
#pragma unroll
      for (int kk = 0; kk < 4; ++kk) {
        float p0 = exp2f(s4[qq][kk][0]), p1 = exp2f(s4[qq][kk][1]);
        float p2 = exp2f(s4[qq][kk][2]), p3 = exp2f(s4[qq][kk][3]);
        ls += (p0 + p1) + (p2 + p3);
        pf[qq][kk][0] = (f16)p0; pf[qq][kk][1] = (f16)p1;
        pf[qq][kk][2] = (f16)p2; pf[qq][kk][3] = (f16)p3;
      }
      l[qq] += ls;
    }
#pragma unroll
    for (int qq = 0; qq < 2; ++qq)
#pragma unroll
      for (int tt = 0; tt < 4; ++tt)
#pragma unroll
        for (int kk = 0; kk < 4; ++kk)
          o[qq][tt] = __builtin_amdgcn_mfma_f32_16x16x16f16(pf[qq][kk], vf[kk][tt], o[qq][tt], 0, 0, 0);
  }

#pragma unroll
  for (int qq = 0; qq < 2; ++qq) {
    float lq = l[qq];
    lq += __shfl_xor(lq, 16);
    lq += __shfl_xor(lq, 32);
    const float inv = 1.0f / lq;
    const float i0 = __shfl(inv, grp * 4 + 0);
    const float i1 = __shfl(inv, grp * 4 + 1);
    const float i2 = __shfl(inv, grp * 4 + 2);
    const float i3 = __shfl(inv, grp * 4 + 3);
    float* flq = fl + qq * 1088;
#pragma unroll
    for (int tt = 0; tt < 4; ++tt) {
      flq[(grp * 4 + 0) * 68 + tt * 16 + qi] = o[qq][tt][0] * i0;
      flq[(grp * 4 + 1) * 68 + tt * 16 + qi] = o[qq][tt][1] * i1;
      flq[(grp * 4 + 2) * 68 + tt * 16 + qi] = o[qq][tt][2] * i2;
      flq[(grp * 4 + 3) * 68 + tt * 16 + qi] = o[qq][tt][3] * i3;
    }
  }
  __syncthreads();
  const int row = lane >> 2, c0 = (lane & 3) * 16;
#pragma unroll
  for (int qq = 0; qq < 2; ++qq) {
    const float* flq = fl + qq * 1088;
    bf16x8 w0, w1;
#pragma unroll
    for (int j = 0; j < 8; ++j) {
      w0[j] = (bf16)flq[row * 68 + c0 + j];
      w1[j] = (bf16)flq[row * 68 + c0 + 8 + j];
    }
    bf16* ob = Ao + (size_t)(q0 + qq * 16 + row) * HIDDEN + h * 64 + c0;
    *(bf16x8*)ob = w0;
    *(bf16x8*)(ob + 8) = w1;
  }
}

// ---------------- launcher ----------------
extern "C" void kernel_launch(void* const* d_in, const int* in_sizes, int n_in,
                              void* d_out, int out_size, void* d_ws, size_t ws_size,
                              hipStream_t stream) {
  (void)in_sizes; (void)n_in; (void)out_size; (void)ws_size;
  const float* hs   = (const float*)d_in[0];
  const float* wqkv = (const float*)d_in[1];
  const float* wd   = (const float*)d_in[2];
  float* out = (float*)d_out;

  char* ws = (char*)d_ws;
  size_t off = 0;
  auto alloc = [&](size_t b) -> char* {
    char* p = ws + off;
    off += (b + 255) & ~(size_t)255;
    return p;
  };
  bf16* Xb     = (bf16*)alloc((size_t)SEQ * HIDDEN * 2);
  float* fused = (float*)alloc((size_t)SEQ * QKV_OUT * 4);
  bf16* Qb     = (bf16*)alloc((size_t)SEQ * HIDDEN * 2);
  bf16* Kf     = (bf16*)alloc((size_t)(SEQ / 16) * 1024 * 2);
  f16*  Vf     = (f16*)alloc((size_t)(SEQ / 16) * 1024 * 2);
  float* cs_tab = (float*)alloc((size_t)SEQ * 64 * 4);
  float* sn_tab = (float*)alloc((size_t)SEQ * 64 * 4);
  bf16* Ao     = (bf16*)fused;  // fused dead after rope/kvprep -> reuse

  {
    int n4 = SEQ * HIDDEN / 4;
    cvt_f32_bf16_k<<<(n4 + 255) / 256, 256, 0, stream>>>(hs, Xb, n4);
  }
  gemm_bt_k<<<dim3(SEQ / 128, (QKV_OUT + 127) / 128), 256, 0, stream>>>(
      Xb, wqkv, fused, HIDDEN, QKV_OUT, QKV_OUT);
  rope_q_k<<<SEQ, 256, 0, stream>>>(fused, Qb, cs_tab, sn_tab);
  kvprep_k<<<SEQ / 16, 64, 0, stream>>>(fused, cs_tab, sn_tab, Kf, Vf);
  attn_k<<<dim3(SEQ / 32, NHEAD), 64, 0, stream>>>(Qb, Kf, Vf, Ao);
  gemm_bt_k<<<dim3(SEQ / 128, (HIDDEN + 127) / 128), 256, 0, stream>>>(
      Ao, wd, out, HIDDEN, HIDDEN, HIDDEN);
}

// Round 10
// 567.460 us; speedup vs baseline: 1.3695x; 1.3695x over previous
//
#include <hip/hip_runtime.h>

// ---- problem constants ----
#define SEQ     2048
#define HIDDEN  4544          // 71 * 64
#define NHEAD   71
#define HD      64
#define QKV_OUT 4672          // (71+2)*64

typedef __bf16    bf16;
typedef _Float16  f16;
typedef __bf16    bf16x8 __attribute__((ext_vector_type(8)));
typedef __bf16    bf16x4 __attribute__((ext_vector_type(4)));
typedef _Float16  f16x4  __attribute__((ext_vector_type(4)));
typedef _Float16  f16x8  __attribute__((ext_vector_type(8)));
typedef float     f32x4  __attribute__((ext_vector_type(4)));

// async global->LDS, 16B per lane. ldsbase must be wave-uniform (HW adds lane*16B);
// the GLOBAL address is per-lane and must be lane-distinct.
__device__ inline void gl2lds16(const void* g, void* ldsbase) {
  __builtin_amdgcn_global_load_lds(
      (const __attribute__((address_space(1))) unsigned int*)g,
      (__attribute__((address_space(3))) unsigned int*)ldsbase,
      16, 0, 0);
}

// ---------------- fused fp32 -> bf16 convert for all three tensors ----------------
// One dispatch instead of three (saves 2 launch gaps; same total HBM traffic).
__global__ void cvt3_k(const float* __restrict__ a, const float* __restrict__ b,
                       const float* __restrict__ c,
                       bf16* __restrict__ oa, bf16* __restrict__ ob, bf16* __restrict__ oc,
                       int na4, int nb4, int nc4) {
  int i = blockIdx.x * blockDim.x + threadIdx.x;
  const float* src; bf16* dst; int idx;
  if (i < na4)             { src = a; dst = oa; idx = i; }
  else if (i < na4 + nb4)  { src = b; dst = ob; idx = i - na4; }
  else if (i < na4 + nb4 + nc4) { src = c; dst = oc; idx = i - na4 - nb4; }
  else return;
  float4 f = ((const float4*)src)[idx];
  bf16x4 o;
  o[0] = (bf16)f.x; o[1] = (bf16)f.y; o[2] = (bf16)f.z; o[3] = (bf16)f.w;
  *(bf16x4*)(dst + (size_t)idx * 4) = o;
}

// ---------------- bt-GEMM, BK=64 (round-4 proven: 128x128 2-phase + T1 swizzle) ----
__global__ __launch_bounds__(256) void gemm_bt_k(const bf16* __restrict__ A,
                                                 const bf16* __restrict__ B,
                                                 float* __restrict__ C,
                                                 int K, int Nmat, int ldc) {
  __shared__ bf16 lA[2][128 * 32];   // [k-half][row*32 + k]
  __shared__ bf16 lB[2][128 * 32];
  const int t = threadIdx.x;
  const int lane = t & 63, w = t >> 6;

  // T1: bijective XCD swizzle (both call sites have nwg % 8 == 0)
  const int gx = gridDim.x;
  const int nwg = gx * gridDim.y;
  const int orig = blockIdx.y * gx + blockIdx.x;
  const int swz = (orig & 7) * (nwg >> 3) + (orig >> 3);
  const int m0 = (swz % gx) * 128;
  const int n0 = (swz / gx) * 128;

  const int wm = (w >> 1) * 64, wn = (w & 1) * 64;
  const int qi = lane & 15, grp = lane >> 4;

  const int r0 = t >> 2;            // 0..63: row within 64-row block
  const int c0 = (t & 3) * 8;       // 0,8,16,24: k offset within 32-slice
  const bf16* gA0 = A + (size_t)(m0 + r0) * K + c0;
  const bf16* gA1 = A + (size_t)(m0 + 64 + r0) * K + c0;
  int bR0 = n0 + r0;      if (bR0 >= Nmat) bR0 = Nmat - 1;
  int bR1 = n0 + 64 + r0; if (bR1 >= Nmat) bR1 = Nmat - 1;
  const bf16* gB0 = B + (size_t)bR0 * K + c0;
  const bf16* gB1 = B + (size_t)bR1 * K + c0;
  bf16* lA00 = &lA[0][0] + w * 512;          // (half0, rows 0-63)
  bf16* lA01 = &lA[0][2048] + w * 512;       // (half0, rows 64-127)
  bf16* lA10 = &lA[1][0] + w * 512;
  bf16* lA11 = &lA[1][2048] + w * 512;
  bf16* lB00 = &lB[0][0] + w * 512;
  bf16* lB01 = &lB[0][2048] + w * 512;
  bf16* lB10 = &lB[1][0] + w * 512;
  bf16* lB11 = &lB[1][2048] + w * 512;

  f32x4 acc[4][4] = {};
  for (int k0 = 0; k0 < K; k0 += 64) {
    __syncthreads();
    gl2lds16(gA0 + k0,      lA00);
    gl2lds16(gA1 + k0,      lA01);
    gl2lds16(gA0 + k0 + 32, lA10);
    gl2lds16(gA1 + k0 + 32, lA11);
    gl2lds16(gB0 + k0,      lB00);
    gl2lds16(gB1 + k0,      lB01);
    gl2lds16(gB0 + k0 + 32, lB10);
    gl2lds16(gB1 + k0 + 32, lB11);
    __syncthreads();
#pragma unroll
    for (int half = 0; half < 2; ++half) {
      bf16x8 af[4], bfv[4];
#pragma unroll
      for (int i = 0; i < 4; ++i)
        af[i] = *(const bf16x8*)&lA[half][(wm + i * 16 + qi) * 32 + grp * 8];
#pragma unroll
      for (int i = 0; i < 4; ++i)
        bfv[i] = *(const bf16x8*)&lB[half][(wn + i * 16 + qi) * 32 + grp * 8];
#pragma unroll
      for (int i = 0; i < 4; ++i)
#pragma unroll
        for (int j = 0; j < 4; ++j)
          acc[i][j] = __builtin_amdgcn_mfma_f32_16x16x32_bf16(af[i], bfv[j], acc[i][j], 0, 0, 0);
    }
  }

#pragma unroll
  for (int i = 0; i < 4; ++i) {
    const int row = m0 + wm + i * 16 + grp * 4;
#pragma unroll
    for (int j = 0; j < 4; ++j) {
      const int col = n0 + wn + j * 16 + qi;
      if (col < Nmat) {
#pragma unroll
        for (int r = 0; r < 4; ++r)
          C[(size_t)(row + r) * ldc + col] = acc[i][j][r];
      }
    }
  }
}

// ---------------- RoPE Q + K + V prep, one kernel per sequence row ----------------
// Scale folds 1/8 AND log2(e) so attention can use exp2 directly.
// Threads 0-63 emit the roped K row straight into Kf's MFMA-fragment layout:
//   Kf(s,d) = (s>>4)*1024 + (d>>5)*512 + ((d>>3)&3)*128 + (s&15)*8 + (d&7)
// Threads 64-127 emit the V row into Vf's layout:
//   Vf(s,d) = (s>>4)*1024 + (d>>5)*512 + ((s>>2)&3)*128 + (d&15)*8 + ((d>>4)&1)*4 + (s&3)
// (both derived from & verified against attn_k's fragment reads). Replaces the
// separate kvprep kernel and the global cs/sn tables.
#define QSCALE 0.18033688f   // 0.125 * 1.4426950408889634
__global__ __launch_bounds__(256) void ropekv_k(const float* __restrict__ fused,
                                                bf16* __restrict__ Qb,
                                                bf16* __restrict__ Kf,
                                                f16* __restrict__ Vf) {
  const int s = blockIdx.x, t = threadIdx.x;
  __shared__ float cs[64], sn[64];
  if (t < 64) {
    int i = t & 31;
    double invf = pow(10000.0, -(double)i / 32.0);
    double ang = (double)s * invf;
    cs[t] = (float)cos(ang);
    sn[t] = (float)sin(ang);
  }
  __syncthreads();
  const float* row = fused + (size_t)s * QKV_OUT;

  if (t < 64) {
    // K row (roped, unscaled)
    const int d = t;
    float x = row[NHEAD * 64 + d], xp = row[NHEAD * 64 + (d ^ 32)];
    float rot = (d < 32) ? -xp : xp;
    Kf[(s >> 4) * 1024 + (d >> 5) * 512 + ((d >> 3) & 3) * 128 + (s & 15) * 8 + (d & 7)] =
        (bf16)(x * cs[d] + rot * sn[d]);
  } else if (t < 128) {
    // V row
    const int d = t - 64;
    Vf[(s >> 4) * 1024 + (d >> 5) * 512 + ((s >> 2) & 3) * 128 + (d & 15) * 8 +
       ((d >> 4) & 1) * 4 + (s & 3)] = (f16)row[(NHEAD + 1) * 64 + d];
  }

  bf16* qrow = Qb + (size_t)s * HIDDEN;
  // 71 heads x 8 float4-chunks of the low half (d<32); pair with d+32.
  // cs[d] == cs[d^32], sn[d] == sn[d^32] by construction.
  for (int u = t; u < NHEAD * 8; u += 256) {
    const int head = u >> 3, c4 = (u & 7) * 4;    // d = c4..c4+3 (<32)
    const int e = head * 64 + c4;
    float4 lo = *(const float4*)(row + e);
    float4 hi = *(const float4*)(row + e + 32);
    float xl[4] = {lo.x, lo.y, lo.z, lo.w};
    float xh[4] = {hi.x, hi.y, hi.z, hi.w};
    bf16x4 qlo, qhi;
#pragma unroll
    for (int j = 0; j < 4; ++j) {
      const float c = cs[c4 + j], n = sn[c4 + j];
      qlo[j] = (bf16)((xl[j] * c - xh[j] * n) * QSCALE);
      qhi[j] = (bf16)((xh[j] * c + xl[j] * n) * QSCALE);
    }
    *(bf16x4*)(qrow + e) = qlo;
    *(bf16x4*)(qrow + e + 32) = qhi;
  }
}

// ---------------- causal MQA flash attention: 1 wave = (head, 32 q rows) ----------
// Round-4/5 proven structure (80 VGPR, no barriers in the kv loop, fl-LDS epilogue).
__global__ __launch_bounds__(64) void attn_k(const bf16* __restrict__ Qb,
                                             const bf16* __restrict__ Kf,
                                             const f16*  __restrict__ Vf,
                                             bf16* __restrict__ Ao) {
  __shared__ float fl[2 * 16 * 68];
  const int h = blockIdx.y;
  const int b32 = gridDim.x - 1 - blockIdx.x;   // big blocks first
  const int lane = threadIdx.x;
  const int qi = lane & 15, grp = lane >> 4;
  const int q0 = b32 * 32;
  const int lastT = b32 >> 1;

  bf16x8 qf[2][2];
#pragma unroll
  for (int qq = 0; qq < 2; ++qq) {
    const bf16* qb = Qb + (size_t)(q0 + qq * 16 + qi) * HIDDEN + h * 64 + grp * 8;
    qf[qq][0] = *(const bf16x8*)qb;
    qf[qq][1] = *(const bf16x8*)(qb + 32);
  }

  f32x4 o[2][4] = {};
  float l[2] = {0.f, 0.f};

  for (int kb = 0; kb <= lastT; ++kb) {
    const bf16* kfp = Kf + (size_t)kb * 4096 + lane * 8;
    bf16x8 kf[4][2];
#pragma unroll
    for (int kk = 0; kk < 4; ++kk) {
      kf[kk][0] = *(const bf16x8*)(kfp + kk * 1024);
      kf[kk][1] = *(const bf16x8*)(kfp + kk * 1024 + 512);
    }
    f32x4 s4[2][4];
#pragma unroll
    for (int qq = 0; qq < 2; ++qq)
#pragma unroll
      for (int kk = 0; kk < 4; ++kk) {
        f32x4 z = {};
        s4[qq][kk] = __builtin_amdgcn_mfma_f32_16x16x32_bf16(kf[kk][0], qf[qq][0], z, 0, 0, 0);
        s4[qq][kk] = __builtin_amdgcn_mfma_f32_16x16x32_bf16(kf[kk][1], qf[qq][1], s4[qq][kk], 0, 0, 0);
      }
    // V: 8 x 16B loads (paired-tt layout) — issued before softmax so latency hides
    const f16* vfp = Vf + (size_t)kb * 4096 + lane * 8;
    f16x4 vf[4][4];
#pragma unroll
    for (int kk = 0; kk < 4; ++kk)
#pragma unroll
      for (int p = 0; p < 2; ++p) {
        f16x8 v8 = *(const f16x8*)(vfp + kk * 1024 + p * 512);
#pragma unroll
        for (int j = 0; j < 4; ++j) {
          vf[kk][2 * p][j]     = v8[j];
          vf[kk][2 * p + 1][j] = v8[4 + j];
        }
      }

    if (kb == lastT) {
      const int dq = q0 - kb * 64 + qi;
#pragma unroll
      for (int qq = 0; qq < 2; ++qq)
#pragma unroll
        for (int kk = 0; kk < 4; ++kk)
#pragma unroll
          for (int r = 0; r < 4; ++r)
            if (kk * 16 + grp * 4 + r > dq + qq * 16) s4[qq][kk][r] = -1e30f;
    }
    // scores pre-scaled by log2(e): exp2 is the raw HW op
    f16x4 pf[2][4];
#pragma unroll
    for (int qq = 0; qq < 2; ++qq) {
      float ls = 0.f;
#pragma unroll
      for (int kk = 0; kk < 4; ++kk) {
        float p0 = exp2f(s4[qq][kk][0]), p1 = exp2f(s4[qq][kk][1]);
        float p2 = exp2f(s4[qq][kk][2]), p3 = exp2f(s4[qq][kk][3]);
        ls += (p0 + p1) + (p2 + p3);
        pf[qq][kk][0] = (f16)p0; pf[qq][kk][1] = (f16)p1;
        pf[qq][kk][2] = (f16)p2; pf[qq][kk][3] = (f16)p3;
      }
      l[qq] += ls;
    }
#pragma unroll
    for (int qq = 0; qq < 2; ++qq)
#pragma unroll
      for (int tt = 0; tt < 4; ++tt)
#pragma unroll
        for (int kk = 0; kk < 4; ++kk)
          o[qq][tt] = __builtin_amdgcn_mfma_f32_16x16x16f16(pf[qq][kk], vf[kk][tt], o[qq][tt], 0, 0, 0);
  }

#pragma unroll
  for (int qq = 0; qq < 2; ++qq) {
    float lq = l[qq];
    lq += __shfl_xor(lq, 16);
    lq += __shfl_xor(lq, 32);
    const float inv = 1.0f / lq;
    const float i0 = __shfl(inv, grp * 4 + 0);
    const float i1 = __shfl(inv, grp * 4 + 1);
    const float i2 = __shfl(inv, grp * 4 + 2);
    const float i3 = __shfl(inv, grp * 4 + 3);
    float* flq = fl + qq * 1088;
#pragma unroll
    for (int tt = 0; tt < 4; ++tt) {
      flq[(grp * 4 + 0) * 68 + tt * 16 + qi] = o[qq][tt][0] * i0;
      flq[(grp * 4 + 1) * 68 + tt * 16 + qi] = o[qq][tt][1] * i1;
      flq[(grp * 4 + 2) * 68 + tt * 16 + qi] = o[qq][tt][2] * i2;
      flq[(grp * 4 + 3) * 68 + tt * 16 + qi] = o[qq][tt][3] * i3;
    }
  }
  __syncthreads();
  const int row = lane >> 2, c0 = (lane & 3) * 16;
#pragma unroll
  for (int qq = 0; qq < 2; ++qq) {
    const float* flq = fl + qq * 1088;
    bf16x8 w0, w1;
#pragma unroll
    for (int j = 0; j < 8; ++j) {
      w0[j] = (bf16)flq[row * 68 + c0 + j];
      w1[j] = (bf16)flq[row * 68 + c0 + 8 + j];
    }
    bf16* ob = Ao + (size_t)(q0 + qq * 16 + row) * HIDDEN + h * 64 + c0;
    *(bf16x8*)ob = w0;
    *(bf16x8*)(ob + 8) = w1;
  }
}

// ---------------- launcher ----------------
extern "C" void kernel_launch(void* const* d_in, const int* in_sizes, int n_in,
                              void* d_out, int out_size, void* d_ws, size_t ws_size,
                              hipStream_t stream) {
  (void)in_sizes; (void)n_in; (void)out_size; (void)ws_size;
  const float* hs   = (const float*)d_in[0];
  const float* wqkv = (const float*)d_in[1];
  const float* wd   = (const float*)d_in[2];
  float* out = (float*)d_out;

  char* ws = (char*)d_ws;
  size_t off = 0;
  auto alloc = [&](size_t b) -> char* {
    char* p = ws + off;
    off += (b + 255) & ~(size_t)255;
    return p;
  };
  bf16* Xb     = (bf16*)alloc((size_t)SEQ * HIDDEN * 2);
  bf16* Wqb    = (bf16*)alloc((size_t)QKV_OUT * HIDDEN * 2);
  bf16* Wdb    = (bf16*)alloc((size_t)HIDDEN * HIDDEN * 2);
  float* fused = (float*)alloc((size_t)SEQ * QKV_OUT * 4);
  bf16* Qb     = (bf16*)alloc((size_t)SEQ * HIDDEN * 2);
  bf16* Kf     = (bf16*)alloc((size_t)(SEQ / 16) * 1024 * 2);
  f16*  Vf     = (f16*)alloc((size_t)(SEQ / 16) * 1024 * 2);
  bf16* Ao     = (bf16*)fused;  // fused dead after ropekv -> reuse

  const int na4 = SEQ * HIDDEN / 4;
  const int nb4 = QKV_OUT * HIDDEN / 4;
  const int nc4 = HIDDEN * HIDDEN / 4;
  cvt3_k<<<(na4 + nb4 + nc4 + 255) / 256, 256, 0, stream>>>(
      hs, wqkv, wd, Xb, Wqb, Wdb, na4, nb4, nc4);
  gemm_bt_k<<<dim3(SEQ / 128, (QKV_OUT + 127) / 128), 256, 0, stream>>>(
      Xb, Wqb, fused, HIDDEN, QKV_OUT, QKV_OUT);
  ropekv_k<<<SEQ, 256, 0, stream>>>(fused, Qb, Kf, Vf);
  attn_k<<<dim3(SEQ / 32, NHEAD), 64, 0, stream>>>(Qb, Kf, Vf, Ao);
  gemm_bt_k<<<dim3(SEQ / 128, (HIDDEN + 127) / 128), 256, 0, stream>>>(
      Ao, Wdb, out, HIDDEN, HIDDEN, HIDDEN);
}